// Round 9
// baseline (327.569 us; speedup 1.0000x reference)
//
#include <hip/hip_runtime.h>
#include <cmath>

#define H 96
#define W 96
#define HW 9216
#define CIN 256
#define COUT 256
#define NB 4
#define NCH 72   // K-chunks of 32 kc
#define NGR 36   // K-groups of 64 kc: g = cc2*9 + k, k-inner

typedef float f32x4 __attribute__((ext_vector_type(4)));
typedef float f32x2 __attribute__((ext_vector_type(2)));
typedef short bf16x8 __attribute__((ext_vector_type(8)));

__device__ __forceinline__ unsigned short f2bf(float f) {
  unsigned int u = __float_as_uint(f);
  u += 0x7fff + ((u >> 16) & 1);  // round-to-nearest-even
  return (unsigned short)(u >> 16);
}
__device__ __forceinline__ float bf2f(unsigned short u) {
  return __uint_as_float(((unsigned int)u) << 16);
}
// unpack 2 packed bf16 -> f32x2 (v_lshl + v_and)
__device__ __forceinline__ f32x2 up2(unsigned int u) {
  f32x2 r;
  r.x = __uint_as_float(u << 16);
  r.y = __uint_as_float(u & 0xffff0000u);
  return r;
}

// ---------------------------------------------------------------------------
// Kernel T: x (N,C,HW) fp32 -> xT (N,HW,C) bf16 via LDS tile.
// ---------------------------------------------------------------------------
__global__ __launch_bounds__(256)
void xt_convert(const float* __restrict__ x, unsigned short* __restrict__ xT) {
  __shared__ unsigned short ls[64][72];
  int tid = threadIdx.x;
  int hwbase = blockIdx.x * 64;
  int cbase  = blockIdx.y * 64;
  int n      = blockIdx.z;

  {
    int cl = tid >> 2, qd = tid & 3;
    const float* src = x + ((size_t)(n * CIN + cbase + cl)) * HW + hwbase + qd * 16;
#pragma unroll
    for (int m = 0; m < 4; ++m) {
      float4 v = *(const float4*)(src + m * 4);
      int hwl = qd * 16 + m * 4;
      ls[hwl + 0][cl] = f2bf(v.x);
      ls[hwl + 1][cl] = f2bf(v.y);
      ls[hwl + 2][cl] = f2bf(v.z);
      ls[hwl + 3][cl] = f2bf(v.w);
    }
  }
  __syncthreads();
  {
    int hw = tid >> 2, part = tid & 3;
    unsigned short* dst = xT + ((size_t)(n * HW + hwbase + hw)) * CIN + cbase + part * 16;
    *(uint4*)(dst + 0) = *(const uint4*)(&ls[hw][part * 16 + 0]);
    *(uint4*)(dst + 8) = *(const uint4*)(&ls[hw][part * 16 + 8]);
  }
}

// ---------------------------------------------------------------------------
// Kernel W1: main weights -> MFMA-A fragment order.
// ---------------------------------------------------------------------------
__global__ __launch_bounds__(256)
void wa_convert(const float* __restrict__ w, unsigned short* __restrict__ Ag) {
  int gid = blockIdx.x * 256 + threadIdx.x;  // < 72*16*64 = 73728
  int ch = gid >> 10;
  int rest = gid & 1023;
  int ot = rest >> 6, l = rest & 63;
  int o = ot * 16 + (l & 15);
  int k = ch >> 3, cc = ch & 7;
  int cbase = cc * 32 + (l >> 4) * 8;
  unsigned short r[8];
#pragma unroll
  for (int j = 0; j < 8; ++j)
    r[j] = f2bf(w[((size_t)o * CIN + cbase + j) * 9 + k]);
  uint4 pk;
  pk.x = (unsigned int)r[0] | ((unsigned int)r[1] << 16);
  pk.y = (unsigned int)r[2] | ((unsigned int)r[3] << 16);
  pk.z = (unsigned int)r[4] | ((unsigned int)r[5] << 16);
  pk.w = (unsigned int)r[6] | ((unsigned int)r[7] << 16);
  *(uint4*)(Ag + (size_t)gid * 8) = pk;
}

// ---------------------------------------------------------------------------
// Kernel W2: offset weights -> A-frag order, padded to 32 rows.
// ---------------------------------------------------------------------------
__global__ __launch_bounds__(256)
void wa2_convert(const float* __restrict__ w_off, unsigned short* __restrict__ Ag2) {
  int gid = blockIdx.x * 256 + threadIdx.x;  // < 72*2*64 = 9216
  int ch = gid >> 7;
  int rest = gid & 127;
  int ot = rest >> 6, l = rest & 63;
  int o = ot * 16 + (l & 15);
  int k = ch >> 3, cc = ch & 7;
  int cbase = cc * 32 + (l >> 4) * 8;
  unsigned short r[8];
#pragma unroll
  for (int j = 0; j < 8; ++j)
    r[j] = (o < 27) ? f2bf(w_off[((size_t)o * CIN + cbase + j) * 9 + k]) : (unsigned short)0;
  uint4 pk;
  pk.x = (unsigned int)r[0] | ((unsigned int)r[1] << 16);
  pk.y = (unsigned int)r[2] | ((unsigned int)r[3] << 16);
  pk.z = (unsigned int)r[4] | ((unsigned int)r[5] << 16);
  pk.w = (unsigned int)r[6] | ((unsigned int)r[7] << 16);
  *(uint4*)(Ag2 + (size_t)gid * 8) = pk;
}

// ---------------------------------------------------------------------------
// Kernel O: offset conv as bf16 MFMA GEMM over xT, BK=64, depth-2 pipeline.
// Block = 256 thr (4 waves) x 64 pixels; group g=(cc2,k) k-inner.
// ---------------------------------------------------------------------------
__global__ __launch_bounds__(256, 4)
void offset_gemm(const unsigned short* __restrict__ xT,
                 const unsigned short* __restrict__ Ag2,
                 const float* __restrict__ b_off,
                 float* __restrict__ py, float* __restrict__ px,
                 float* __restrict__ mk) {
  __shared__ int sPos[9][64];
  __shared__ unsigned short sB[2][4096];

  int tid = threadIdx.x;
  int wv = tid >> 6, lane = tid & 63, quad = lane >> 4, l16 = lane & 15;
  int pixBase = blockIdx.x * 64;
  int n = blockIdx.y;
  const unsigned short* xTn = xT + (size_t)n * HW * CIN;

  if (tid < 64) {
    int hwp = pixBase + tid;
    int hh = hwp / W, wx = hwp % W;
#pragma unroll
    for (int ty = 0; ty < 3; ++ty) {
#pragma unroll
      for (int tx = 0; tx < 3; ++tx) {
        int iy = hh + ty - 1, ix = wx + tx - 1;
        bool ok = (iy >= 0) && (iy < H) && (ix >= 0) && (ix < W);
        sPos[ty * 3 + tx][tid] = ok ? (iy * W + ix) : -1;
      }
    }
  }
  __syncthreads();

  int pix0 = tid >> 3, ck0 = tid & 7;
  int pix1 = 32 + (tid >> 3);
  int a0 = (ck0 >> 2) * 2048 + (pix0 >> 4) * 512 + ((ck0 & 3) * 16 + ((pix0 & 15) ^ (ck0 & 3))) * 8;
  int a1 = (ck0 >> 2) * 2048 + (pix1 >> 4) * 512 + ((ck0 & 3) * 16 + ((pix1 & 15) ^ (ck0 & 3))) * 8;

  f32x4 acc[2];
  acc[0] = (f32x4){0.f, 0.f, 0.f, 0.f};
  acc[1] = (f32x4){0.f, 0.f, 0.f, 0.f};

  uint4 dA[2], dB[2];
  auto issue = [&](int g, uint4* d) {
    int k = g % 9, c2 = g / 9;
    int p0 = sPos[k][pix0], p1 = sPos[k][pix1];
    d[0] = (uint4){0, 0, 0, 0};
    d[1] = (uint4){0, 0, 0, 0};
    if (p0 >= 0) d[0] = *(const uint4*)(xTn + (size_t)p0 * CIN + c2 * 64 + ck0 * 8);
    if (p1 >= 0) d[1] = *(const uint4*)(xTn + (size_t)p1 * CIN + c2 * 64 + ck0 * 8);
  };

  bf16x8 afrA[4], afrB[4];
  auto aload = [&](int g, bf16x8* dst) {
    int k = g % 9, c2 = g / 9;
    int ch = k * 8 + c2 * 2;
#pragma unroll
    for (int s = 0; s < 2; ++s)
#pragma unroll
      for (int ot = 0; ot < 2; ++ot)
        dst[s * 2 + ot] = *(const bf16x8*)(Ag2 + ((size_t)((ch + s) * 2 + ot) * 64 + lane) * 8);
  };

  int rdAddr0 = wv * 512 + (quad * 16 + (l16 ^ quad)) * 8;
  auto mfmaPhase = [&](int buf, bf16x8* afr) {
#pragma unroll
    for (int s = 0; s < 2; ++s) {
      bf16x8 bfr = *(const bf16x8*)(&sB[buf][s * 2048 + rdAddr0]);
      acc[0] = __builtin_amdgcn_mfma_f32_16x16x32_bf16(afr[s * 2 + 0], bfr, acc[0], 0, 0, 0);
      acc[1] = __builtin_amdgcn_mfma_f32_16x16x32_bf16(afr[s * 2 + 1], bfr, acc[1], 0, 0, 0);
    }
  };
  auto store = [&](uint4* d, int buf) {
    *(uint4*)(&sB[buf][a0]) = d[0];
    *(uint4*)(&sB[buf][a1]) = d[1];
  };

  // prologue
  issue(0, dA);
  aload(0, afrA);
  store(dA, 0);
  issue(1, dB);       // depth-2 seed
  __syncthreads();

  for (int g = 0; g < NGR; g += 2) {
    // even g: buf0 + afrA; prefetch g+2 -> dA; stage dB(g+1) -> buf1
    if (g + 2 < NGR) issue(g + 2, dA);
    aload(g + 1, afrB);
    mfmaPhase(0, afrA);
    store(dB, 1);
    __syncthreads();

    // odd g+1: buf1 + afrB; prefetch g+3 -> dB; stage dA(g+2) -> buf0
    if (g + 3 < NGR) issue(g + 3, dB);
    if (g + 2 < NGR) aload(g + 2, afrA);
    mfmaPhase(1, afrB);
    if (g + 2 < NGR) {
      store(dA, 0);
      __syncthreads();
    }
  }

  // Epilogue
  int pix = pixBase + wv * 16 + l16;
  int he = pix / W, we = pix % W;
#pragma unroll
  for (int ot = 0; ot < 2; ++ot) {
#pragma unroll
    for (int r = 0; r < 4; ++r) {
      int kk = ot * 16 + quad * 4 + r;
      if (kk >= 27) continue;
      float v = acc[ot][r] + b_off[kk];
      if (kk < 9) {
        py[(size_t)(n * 9 + kk) * HW + pix] = v + (float)he + (float)(kk / 3 - 1);
      } else if (kk < 18) {
        int j = kk - 9;
        px[(size_t)(n * 9 + j) * HW + pix] = v + (float)we + (float)(j % 3 - 1);
      } else {
        mk[(size_t)(n * 9 + (kk - 18)) * HW + pix] = 1.f / (1.f + expf(-v));
      }
    }
  }
}

// ---------------------------------------------------------------------------
// Kernel G: FUSED bilinear-sample + bf16 MFMA GEMM, BK=64, coalesced gathers,
// DEPTH-2 pipeline: corner loads for g+2 issued at g (full-group latency
// cover); parity A-frag sets; packed-f32 blend. 1 barrier/group.
// ---------------------------------------------------------------------------
__global__ __launch_bounds__(512, 4)
void fused_gemm(const unsigned short* __restrict__ xT,
                const unsigned short* __restrict__ Ag,
                const float* __restrict__ py,
                const float* __restrict__ px,
                const float* __restrict__ mk,
                unsigned short* __restrict__ yb,
                float* __restrict__ sumArr, float* __restrict__ sqArr) {
  __shared__ int   sIdx[9][4][64];
  __shared__ float sWgt[9][4][64];
  __shared__ unsigned short sB[2][4096];

  int tid = threadIdx.x;
  int wv = tid >> 6, lane = tid & 63, quad = lane >> 4, l16 = lane & 15;
  int pixBase = blockIdx.x * 64;
  int n = blockIdx.y;
  const unsigned short* xTn = xT + (size_t)n * HW * CIN;

  // ---- prologue: corner indices + mask-folded weights, 64 pix x 9 taps
  {
    int pix0 = tid & 63;
    int k0 = tid >> 6;
#pragma unroll
    for (int rep = 0; rep < 2; ++rep) {
      int k = (rep == 0) ? k0 : 8;
      if (rep == 1 && tid >= 64) break;
      int off = (n * 9 + k) * HW + pixBase + pix0;
      float fy = py[off], fx = px[off], fm = mk[off];
      float y0f = floorf(fy), x0f = floorf(fx);
      float ly = fy - y0f, lx = fx - x0f;
      int y0 = (int)y0f, x0 = (int)x0f;
      int cy0 = min(max(y0, 0), H - 1), cy1 = min(max(y0 + 1, 0), H - 1);
      int cx0 = min(max(x0, 0), W - 1), cx1 = min(max(x0 + 1, 0), W - 1);
      float vy0 = (y0 >= 0 && y0 <= H - 1) ? 1.f : 0.f;
      float vy1 = (y0 + 1 >= 0 && y0 + 1 <= H - 1) ? 1.f : 0.f;
      float vx0 = (x0 >= 0 && x0 <= W - 1) ? 1.f : 0.f;
      float vx1 = (x0 + 1 >= 0 && x0 + 1 <= W - 1) ? 1.f : 0.f;
      sIdx[k][0][pix0] = cy0 * W + cx0;
      sIdx[k][1][pix0] = cy0 * W + cx1;
      sIdx[k][2][pix0] = cy1 * W + cx0;
      sIdx[k][3][pix0] = cy1 * W + cx1;
      sWgt[k][0][pix0] = (1.f - ly) * (1.f - lx) * fm * vy0 * vx0;
      sWgt[k][1][pix0] = (1.f - ly) * lx * fm * vy0 * vx1;
      sWgt[k][2][pix0] = ly * (1.f - lx) * fm * vy1 * vx0;
      sWgt[k][3][pix0] = ly * lx * fm * vy1 * vx1;
    }
  }
  __syncthreads();

  // sampling role (coalesced): 4 consecutive lanes = 1 corner-row line
  int pixS  = ((wv & 3) << 4) | (lane >> 2);  // 0..63
  int qS    = lane & 3;
  int chunk = ((wv >> 2) << 2) | qS;          // 0..7
  int co    = chunk * 8;
  int sAddr = (chunk >> 2) * 2048 + (wv & 3) * 512 + (qS * 16 + ((lane >> 2) ^ qS)) * 8;

  f32x4 acc[2][4];
#pragma unroll
  for (int i = 0; i < 2; ++i)
#pragma unroll
    for (int pt = 0; pt < 4; ++pt) acc[i][pt] = (f32x4){0.f, 0.f, 0.f, 0.f};

  uint4 cnA[4], cnB[4];
  float wgA[4], wgB[4];
  auto issue = [&](int g, uint4* cn, float* wt) {
    int k = g % 9, c2 = g / 9;
    int i0 = sIdx[k][0][pixS], i1 = sIdx[k][1][pixS];
    int i2 = sIdx[k][2][pixS], i3 = sIdx[k][3][pixS];
    int coff = c2 * 64 + co;
    cn[0] = *(const uint4*)(xTn + (size_t)i0 * CIN + coff);
    cn[1] = *(const uint4*)(xTn + (size_t)i1 * CIN + coff);
    cn[2] = *(const uint4*)(xTn + (size_t)i2 * CIN + coff);
    cn[3] = *(const uint4*)(xTn + (size_t)i3 * CIN + coff);
    wt[0] = sWgt[k][0][pixS]; wt[1] = sWgt[k][1][pixS];
    wt[2] = sWgt[k][2][pixS]; wt[3] = sWgt[k][3][pixS];
  };

  auto blendOne = [&](unsigned int u0, unsigned int u1, unsigned int u2,
                      unsigned int u3, const float* wt) -> unsigned int {
    f32x2 s = up2(u0) * wt[0];       // contracts to v_pk_fma chain
    s += up2(u1) * wt[1];
    s += up2(u2) * wt[2];
    s += up2(u3) * wt[3];
    return (unsigned int)f2bf(s.x) | ((unsigned int)f2bf(s.y) << 16);
  };
  auto blendStore = [&](uint4* cn, const float* wt, int buf) {
    uint4 r;
    r.x = blendOne(cn[0].x, cn[1].x, cn[2].x, cn[3].x, wt);
    r.y = blendOne(cn[0].y, cn[1].y, cn[2].y, cn[3].y, wt);
    r.z = blendOne(cn[0].z, cn[1].z, cn[2].z, cn[3].z, wt);
    r.w = blendOne(cn[0].w, cn[1].w, cn[2].w, cn[3].w, wt);
    *(uint4*)(&sB[buf][sAddr]) = r;
  };

  bf16x8 afrA[4], afrB[4];
  auto aload = [&](int g, bf16x8* dst) {
    int k = g % 9, c2 = g / 9;
    int ch = k * 8 + c2 * 2;
#pragma unroll
    for (int s = 0; s < 2; ++s)
#pragma unroll
      for (int ot = 0; ot < 2; ++ot)
        dst[s * 2 + ot] = *(const bf16x8*)(Ag + ((size_t)((ch + s) * 16 + 2 * wv + ot) * 64 + lane) * 8);
  };

  int rdBase = (quad * 16 + (l16 ^ quad)) * 8;
  auto mfmaPhase = [&](int buf, bf16x8* afr) {
#pragma unroll
    for (int s = 0; s < 2; ++s) {
      bf16x8 bfr[4];
#pragma unroll
      for (int pt = 0; pt < 4; ++pt)
        bfr[pt] = *(const bf16x8*)(&sB[buf][s * 2048 + pt * 512 + rdBase]);
#pragma unroll
      for (int pt = 0; pt < 4; ++pt) {
        acc[0][pt] = __builtin_amdgcn_mfma_f32_16x16x32_bf16(afr[s * 2 + 0], bfr[pt], acc[0][pt], 0, 0, 0);
        acc[1][pt] = __builtin_amdgcn_mfma_f32_16x16x32_bf16(afr[s * 2 + 1], bfr[pt], acc[1][pt], 0, 0, 0);
      }
    }
  };

  // prologue: g0 staged to buf0; g1 loads in flight
  issue(0, cnA, wgA);
  aload(0, afrA);
  blendStore(cnA, wgA, 0);
  issue(1, cnB, wgB);       // depth-2 seed
  __syncthreads();

  for (int g = 0; g < NGR; g += 2) {
    // even g: consume buf0 with afrA; prefetch g+2 -> cnA; stage cnB(g+1) -> buf1
    if (g + 2 < NGR) issue(g + 2, cnA, wgA);
    aload(g + 1, afrB);
    mfmaPhase(0, afrA);
    blendStore(cnB, wgB, 1);
    __syncthreads();

    // odd g+1: consume buf1 with afrB; prefetch g+3 -> cnB; stage cnA(g+2) -> buf0
    if (g + 3 < NGR) issue(g + 3, cnB, wgB);
    if (g + 2 < NGR) aload(g + 2, afrA);
    mfmaPhase(1, afrB);
    if (g + 2 < NGR) {
      blendStore(cnA, wgA, 0);
      __syncthreads();
    }
  }

  // Epilogue: D col = l16 (pix), row = quad*4 + r (o within 16-tile)
#pragma unroll
  for (int ot = 0; ot < 2; ++ot) {
#pragma unroll
    for (int r = 0; r < 4; ++r) {
      int o = (2 * wv + ot) * 16 + quad * 4 + r;
      unsigned short* rowp = yb + (size_t)(n * COUT + o) * HW + pixBase;
      float s = 0.f, q = 0.f;
#pragma unroll
      for (int pt = 0; pt < 4; ++pt) {
        float v = acc[ot][pt][r];
        rowp[pt * 16 + l16] = f2bf(v);
        s += v;
        q = fmaf(v, v, q);
      }
#pragma unroll
      for (int m = 8; m >= 1; m >>= 1) {
        s += __shfl_xor(s, m, 64);
        q += __shfl_xor(q, m, 64);
      }
      if (l16 == 0) {
        atomicAdd(&sumArr[o], s);
        atomicAdd(&sqArr[o], q);
      }
    }
  }
}

// ---------------------------------------------------------------------------
// BN finalize + apply (bf16 y -> fp32 out)
// ---------------------------------------------------------------------------
__global__ __launch_bounds__(256)
void bn_finalize(const float* __restrict__ sumArr, const float* __restrict__ sqArr,
                 const float* __restrict__ gamma, const float* __restrict__ beta,
                 float* __restrict__ scaleArr, float* __restrict__ shiftArr) {
  int o = threadIdx.x;
  const float inv = 1.f / (float)(NB * HW);
  float mean = sumArr[o] * inv;
  float var = sqArr[o] * inv - mean * mean;
  float sc = rsqrtf(var + 1e-5f) * gamma[o];
  scaleArr[o] = sc;
  shiftArr[o] = beta[o] - mean * sc;
}

__global__ __launch_bounds__(256)
void bn_apply(const unsigned short* __restrict__ yb,
              float* __restrict__ out,
              const float* __restrict__ scaleArr,
              const float* __restrict__ shiftArr) {
  int gid = blockIdx.x * 256 + threadIdx.x;  // < NB*COUT*HW/8
  int base = gid * 8;
  int o = (base / HW) % COUT;
  float scale = scaleArr[o], shift = shiftArr[o];
  uint4 v = ((const uint4*)yb)[gid];
  float4 a, b;
  a.x = fmaxf(fmaf(bf2f((unsigned short)(v.x & 0xffff)), scale, shift), 0.f);
  a.y = fmaxf(fmaf(bf2f((unsigned short)(v.x >> 16)), scale, shift), 0.f);
  a.z = fmaxf(fmaf(bf2f((unsigned short)(v.y & 0xffff)), scale, shift), 0.f);
  a.w = fmaxf(fmaf(bf2f((unsigned short)(v.y >> 16)), scale, shift), 0.f);
  b.x = fmaxf(fmaf(bf2f((unsigned short)(v.z & 0xffff)), scale, shift), 0.f);
  b.y = fmaxf(fmaf(bf2f((unsigned short)(v.z >> 16)), scale, shift), 0.f);
  b.z = fmaxf(fmaf(bf2f((unsigned short)(v.w & 0xffff)), scale, shift), 0.f);
  b.w = fmaxf(fmaf(bf2f((unsigned short)(v.w >> 16)), scale, shift), 0.f);
  *(float4*)&out[base] = a;
  *(float4*)&out[base + 4] = b;
}

// ---------------------------------------------------------------------------
extern "C" void kernel_launch(void* const* d_in, const int* in_sizes, int n_in,
                              void* d_out, int out_size, void* d_ws, size_t ws_size,
                              hipStream_t stream) {
  const float* x     = (const float*)d_in[0];
  const float* w_off = (const float*)d_in[1];
  const float* b_off = (const float*)d_in[2];
  const float* w     = (const float*)d_in[3];
  // d_in[4] = b : cancels exactly in BN mean-subtraction
  const float* gamma = (const float*)d_in[5];
  const float* beta  = (const float*)d_in[6];
  float* out = (float*)d_out;

  float* ws = (float*)d_ws;
  float* py = ws;                          // 331776 f
  float* px = py + 331776;
  float* mk = px + 331776;
  unsigned short* Ag  = (unsigned short*)(mk + 331776);  // 589824 u16
  unsigned short* Ag2 = Ag + 589824;                     // 73728 u16
  float* sumArr   = (float*)(Ag2 + 73728);
  float* sqArr    = sumArr + 256;
  float* scaleArr = sqArr + 256;
  float* shiftArr = scaleArr + 256;
  unsigned short* yb = (unsigned short*)(shiftArr + 256);  // 9437184 u16
  unsigned short* xT = yb + 9437184;                       // 9437184 u16

  hipMemsetAsync(sumArr, 0, 512 * sizeof(float), stream);

  dim3 gT(HW / 64, CIN / 64, NB);
  xt_convert<<<gT, 256, 0, stream>>>(x, xT);

  wa_convert<<<(NCH * 16 * 64) / 256, 256, 0, stream>>>(w, Ag);
  wa2_convert<<<(NCH * 2 * 64) / 256, 256, 0, stream>>>(w_off, Ag2);

  dim3 gO(HW / 64, NB);
  offset_gemm<<<gO, 256, 0, stream>>>(xT, Ag2, b_off, py, px, mk);

  dim3 gG(HW / 64, NB);
  fused_gemm<<<gG, 512, 0, stream>>>(xT, Ag, py, px, mk, yb, sumArr, sqArr);

  bn_finalize<<<1, 256, 0, stream>>>(sumArr, sqArr, gamma, beta, scaleArr, shiftArr);
  bn_apply<<<(NB * COUT * HW / 8) / 256, 256, 0, stream>>>(yb, out, scaleArr, shiftArr);
}

// Round 10
// 272.285 us; speedup vs baseline: 1.2030x; 1.2030x over previous
//
#include <hip/hip_runtime.h>
#include <cmath>

#define H 96
#define W 96
#define HW 9216
#define CIN 256
#define COUT 256
#define NB 4
#define NCH 72   // K-chunks of 32 kc
#define NGR 36   // K-groups of 64 kc: g = cc2*9 + k, k-inner

typedef float f32x4 __attribute__((ext_vector_type(4)));
typedef float f32x2 __attribute__((ext_vector_type(2)));
typedef short bf16x8 __attribute__((ext_vector_type(8)));

__device__ __forceinline__ unsigned short f2bf(float f) {
  unsigned int u = __float_as_uint(f);
  u += 0x7fff + ((u >> 16) & 1);  // round-to-nearest-even
  return (unsigned short)(u >> 16);
}
__device__ __forceinline__ float bf2f(unsigned short u) {
  return __uint_as_float(((unsigned int)u) << 16);
}
__device__ __forceinline__ f32x2 up2(unsigned int u) {
  f32x2 r;
  r.x = __uint_as_float(u << 16);
  r.y = __uint_as_float(u & 0xffff0000u);
  return r;
}

// ---------------------------------------------------------------------------
// Kernel T: x (N,C,HW) fp32 -> xT (N,HW,C) bf16 via LDS tile.
// ---------------------------------------------------------------------------
__global__ __launch_bounds__(256)
void xt_convert(const float* __restrict__ x, unsigned short* __restrict__ xT) {
  __shared__ unsigned short ls[64][72];
  int tid = threadIdx.x;
  int hwbase = blockIdx.x * 64;
  int cbase  = blockIdx.y * 64;
  int n      = blockIdx.z;

  {
    int cl = tid >> 2, qd = tid & 3;
    const float* src = x + ((size_t)(n * CIN + cbase + cl)) * HW + hwbase + qd * 16;
#pragma unroll
    for (int m = 0; m < 4; ++m) {
      float4 v = *(const float4*)(src + m * 4);
      int hwl = qd * 16 + m * 4;
      ls[hwl + 0][cl] = f2bf(v.x);
      ls[hwl + 1][cl] = f2bf(v.y);
      ls[hwl + 2][cl] = f2bf(v.z);
      ls[hwl + 3][cl] = f2bf(v.w);
    }
  }
  __syncthreads();
  {
    int hw = tid >> 2, part = tid & 3;
    unsigned short* dst = xT + ((size_t)(n * HW + hwbase + hw)) * CIN + cbase + part * 16;
    *(uint4*)(dst + 0) = *(const uint4*)(&ls[hw][part * 16 + 0]);
    *(uint4*)(dst + 8) = *(const uint4*)(&ls[hw][part * 16 + 8]);
  }
}

// ---------------------------------------------------------------------------
// Kernel W1: main weights -> MFMA-A fragment order.
// ---------------------------------------------------------------------------
__global__ __launch_bounds__(256)
void wa_convert(const float* __restrict__ w, unsigned short* __restrict__ Ag) {
  int gid = blockIdx.x * 256 + threadIdx.x;  // < 72*16*64 = 73728
  int ch = gid >> 10;
  int rest = gid & 1023;
  int ot = rest >> 6, l = rest & 63;
  int o = ot * 16 + (l & 15);
  int k = ch >> 3, cc = ch & 7;
  int cbase = cc * 32 + (l >> 4) * 8;
  unsigned short r[8];
#pragma unroll
  for (int j = 0; j < 8; ++j)
    r[j] = f2bf(w[((size_t)o * CIN + cbase + j) * 9 + k]);
  uint4 pk;
  pk.x = (unsigned int)r[0] | ((unsigned int)r[1] << 16);
  pk.y = (unsigned int)r[2] | ((unsigned int)r[3] << 16);
  pk.z = (unsigned int)r[4] | ((unsigned int)r[5] << 16);
  pk.w = (unsigned int)r[6] | ((unsigned int)r[7] << 16);
  *(uint4*)(Ag + (size_t)gid * 8) = pk;
}

// ---------------------------------------------------------------------------
// Kernel W2: offset weights -> A-frag order, padded to 32 rows.
// ---------------------------------------------------------------------------
__global__ __launch_bounds__(256)
void wa2_convert(const float* __restrict__ w_off, unsigned short* __restrict__ Ag2) {
  int gid = blockIdx.x * 256 + threadIdx.x;  // < 72*2*64 = 9216
  int ch = gid >> 7;
  int rest = gid & 127;
  int ot = rest >> 6, l = rest & 63;
  int o = ot * 16 + (l & 15);
  int k = ch >> 3, cc = ch & 7;
  int cbase = cc * 32 + (l >> 4) * 8;
  unsigned short r[8];
#pragma unroll
  for (int j = 0; j < 8; ++j)
    r[j] = (o < 27) ? f2bf(w_off[((size_t)o * CIN + cbase + j) * 9 + k]) : (unsigned short)0;
  uint4 pk;
  pk.x = (unsigned int)r[0] | ((unsigned int)r[1] << 16);
  pk.y = (unsigned int)r[2] | ((unsigned int)r[3] << 16);
  pk.z = (unsigned int)r[4] | ((unsigned int)r[5] << 16);
  pk.w = (unsigned int)r[6] | ((unsigned int)r[7] << 16);
  *(uint4*)(Ag2 + (size_t)gid * 8) = pk;
}

// ---------------------------------------------------------------------------
// Kernel O: offset conv as bf16 MFMA GEMM over xT, BK=64, depth-2 pipeline,
// single A-frag set (reloaded post-MFMA, in flight across blend+barrier).
// ---------------------------------------------------------------------------
__global__ __launch_bounds__(256, 4)
void offset_gemm(const unsigned short* __restrict__ xT,
                 const unsigned short* __restrict__ Ag2,
                 const float* __restrict__ b_off,
                 float* __restrict__ py, float* __restrict__ px,
                 float* __restrict__ mk) {
  __shared__ int sPos[9][64];
  __shared__ unsigned short sB[2][4096];

  int tid = threadIdx.x;
  int wv = tid >> 6, lane = tid & 63, quad = lane >> 4, l16 = lane & 15;
  int pixBase = blockIdx.x * 64;
  int n = blockIdx.y;
  const unsigned short* xTn = xT + (size_t)n * HW * CIN;

  if (tid < 64) {
    int hwp = pixBase + tid;
    int hh = hwp / W, wx = hwp % W;
#pragma unroll
    for (int ty = 0; ty < 3; ++ty) {
#pragma unroll
      for (int tx = 0; tx < 3; ++tx) {
        int iy = hh + ty - 1, ix = wx + tx - 1;
        bool ok = (iy >= 0) && (iy < H) && (ix >= 0) && (ix < W);
        sPos[ty * 3 + tx][tid] = ok ? (iy * W + ix) : -1;
      }
    }
  }
  __syncthreads();

  int pix0 = tid >> 3, ck0 = tid & 7;
  int pix1 = 32 + (tid >> 3);
  int a0 = (ck0 >> 2) * 2048 + (pix0 >> 4) * 512 + ((ck0 & 3) * 16 + ((pix0 & 15) ^ (ck0 & 3))) * 8;
  int a1 = (ck0 >> 2) * 2048 + (pix1 >> 4) * 512 + ((ck0 & 3) * 16 + ((pix1 & 15) ^ (ck0 & 3))) * 8;

  f32x4 acc[2];
  acc[0] = (f32x4){0.f, 0.f, 0.f, 0.f};
  acc[1] = (f32x4){0.f, 0.f, 0.f, 0.f};

  uint4 dA[2], dB[2];
  auto issue = [&](int g, uint4* d) {
    int k = g % 9, c2 = g / 9;
    int p0 = sPos[k][pix0], p1 = sPos[k][pix1];
    d[0] = (uint4){0, 0, 0, 0};
    d[1] = (uint4){0, 0, 0, 0};
    if (p0 >= 0) d[0] = *(const uint4*)(xTn + (size_t)p0 * CIN + c2 * 64 + ck0 * 8);
    if (p1 >= 0) d[1] = *(const uint4*)(xTn + (size_t)p1 * CIN + c2 * 64 + ck0 * 8);
  };

  bf16x8 afr[4];
  auto aload = [&](int g) {
    int k = g % 9, c2 = g / 9;
    int ch = k * 8 + c2 * 2;
#pragma unroll
    for (int s = 0; s < 2; ++s)
#pragma unroll
      for (int ot = 0; ot < 2; ++ot)
        afr[s * 2 + ot] = *(const bf16x8*)(Ag2 + ((size_t)((ch + s) * 2 + ot) * 64 + lane) * 8);
  };

  int rdAddr0 = wv * 512 + (quad * 16 + (l16 ^ quad)) * 8;
  auto mfmaPhase = [&](int buf) {
#pragma unroll
    for (int s = 0; s < 2; ++s) {
      bf16x8 bfr = *(const bf16x8*)(&sB[buf][s * 2048 + rdAddr0]);
      acc[0] = __builtin_amdgcn_mfma_f32_16x16x32_bf16(afr[s * 2 + 0], bfr, acc[0], 0, 0, 0);
      acc[1] = __builtin_amdgcn_mfma_f32_16x16x32_bf16(afr[s * 2 + 1], bfr, acc[1], 0, 0, 0);
    }
  };
  auto store = [&](uint4* d, int buf) {
    *(uint4*)(&sB[buf][a0]) = d[0];
    *(uint4*)(&sB[buf][a1]) = d[1];
  };

  // prologue
  issue(0, dA);
  aload(0);
  store(dA, 0);
  issue(1, dB);       // depth-2 seed
  __syncthreads();

  for (int g = 0; g < NGR; g += 2) {
    // even g: consume buf0 (group g); prefetch g+2 -> dA; stage dB(g+1) -> buf1
    if (g + 2 < NGR) issue(g + 2, dA);
    mfmaPhase(0);
    aload(g + 1);               // in flight across store+barrier
    store(dB, 1);
    __syncthreads();

    // odd g+1: consume buf1; prefetch g+3 -> dB; stage dA(g+2) -> buf0
    if (g + 3 < NGR) issue(g + 3, dB);
    mfmaPhase(1);
    if (g + 2 < NGR) {
      aload(g + 2);
      store(dA, 0);
      __syncthreads();
    }
  }

  // Epilogue
  int pix = pixBase + wv * 16 + l16;
  int he = pix / W, we = pix % W;
#pragma unroll
  for (int ot = 0; ot < 2; ++ot) {
#pragma unroll
    for (int r = 0; r < 4; ++r) {
      int kk = ot * 16 + quad * 4 + r;
      if (kk >= 27) continue;
      float v = acc[ot][r] + b_off[kk];
      if (kk < 9) {
        py[(size_t)(n * 9 + kk) * HW + pix] = v + (float)he + (float)(kk / 3 - 1);
      } else if (kk < 18) {
        int j = kk - 9;
        px[(size_t)(n * 9 + j) * HW + pix] = v + (float)we + (float)(j % 3 - 1);
      } else {
        mk[(size_t)(n * 9 + (kk - 18)) * HW + pix] = 1.f / (1.f + expf(-v));
      }
    }
  }
}

// ---------------------------------------------------------------------------
// Kernel G: FUSED bilinear-sample + bf16 MFMA GEMM, BK=64, coalesced gathers,
// depth-2 corner prefetch, SINGLE A-frag set (reloaded post-MFMA phase so the
// loads fly across blend+barrier). Register budget ~110 < 128 -> no spill,
// 2 blocks/CU co-resident.
// ---------------------------------------------------------------------------
__global__ __launch_bounds__(512, 4)
void fused_gemm(const unsigned short* __restrict__ xT,
                const unsigned short* __restrict__ Ag,
                const float* __restrict__ py,
                const float* __restrict__ px,
                const float* __restrict__ mk,
                unsigned short* __restrict__ yb,
                float* __restrict__ sumArr, float* __restrict__ sqArr) {
  __shared__ int   sIdx[9][4][64];
  __shared__ float sWgt[9][4][64];
  __shared__ unsigned short sB[2][4096];

  int tid = threadIdx.x;
  int wv = tid >> 6, lane = tid & 63, quad = lane >> 4, l16 = lane & 15;
  int pixBase = blockIdx.x * 64;
  int n = blockIdx.y;
  const unsigned short* xTn = xT + (size_t)n * HW * CIN;

  // ---- prologue: corner indices + mask-folded weights, 64 pix x 9 taps
  {
    int pix0 = tid & 63;
    int k0 = tid >> 6;
#pragma unroll
    for (int rep = 0; rep < 2; ++rep) {
      int k = (rep == 0) ? k0 : 8;
      if (rep == 1 && tid >= 64) break;
      int off = (n * 9 + k) * HW + pixBase + pix0;
      float fy = py[off], fx = px[off], fm = mk[off];
      float y0f = floorf(fy), x0f = floorf(fx);
      float ly = fy - y0f, lx = fx - x0f;
      int y0 = (int)y0f, x0 = (int)x0f;
      int cy0 = min(max(y0, 0), H - 1), cy1 = min(max(y0 + 1, 0), H - 1);
      int cx0 = min(max(x0, 0), W - 1), cx1 = min(max(x0 + 1, 0), W - 1);
      float vy0 = (y0 >= 0 && y0 <= H - 1) ? 1.f : 0.f;
      float vy1 = (y0 + 1 >= 0 && y0 + 1 <= H - 1) ? 1.f : 0.f;
      float vx0 = (x0 >= 0 && x0 <= W - 1) ? 1.f : 0.f;
      float vx1 = (x0 + 1 >= 0 && x0 + 1 <= W - 1) ? 1.f : 0.f;
      sIdx[k][0][pix0] = cy0 * W + cx0;
      sIdx[k][1][pix0] = cy0 * W + cx1;
      sIdx[k][2][pix0] = cy1 * W + cx0;
      sIdx[k][3][pix0] = cy1 * W + cx1;
      sWgt[k][0][pix0] = (1.f - ly) * (1.f - lx) * fm * vy0 * vx0;
      sWgt[k][1][pix0] = (1.f - ly) * lx * fm * vy0 * vx1;
      sWgt[k][2][pix0] = ly * (1.f - lx) * fm * vy1 * vx0;
      sWgt[k][3][pix0] = ly * lx * fm * vy1 * vx1;
    }
  }
  __syncthreads();

  // sampling role (coalesced): 4 consecutive lanes = 1 corner-row line
  int pixS  = ((wv & 3) << 4) | (lane >> 2);  // 0..63
  int qS    = lane & 3;
  int chunk = ((wv >> 2) << 2) | qS;          // 0..7
  int co    = chunk * 8;
  int sAddr = (chunk >> 2) * 2048 + (wv & 3) * 512 + (qS * 16 + ((lane >> 2) ^ qS)) * 8;

  f32x4 acc[2][4];
#pragma unroll
  for (int i = 0; i < 2; ++i)
#pragma unroll
    for (int pt = 0; pt < 4; ++pt) acc[i][pt] = (f32x4){0.f, 0.f, 0.f, 0.f};

  uint4 cnA[4], cnB[4];
  float wgA[4], wgB[4];
  auto issue = [&](int g, uint4* cn, float* wt) {
    int k = g % 9, c2 = g / 9;
    int i0 = sIdx[k][0][pixS], i1 = sIdx[k][1][pixS];
    int i2 = sIdx[k][2][pixS], i3 = sIdx[k][3][pixS];
    int coff = c2 * 64 + co;
    cn[0] = *(const uint4*)(xTn + (size_t)i0 * CIN + coff);
    cn[1] = *(const uint4*)(xTn + (size_t)i1 * CIN + coff);
    cn[2] = *(const uint4*)(xTn + (size_t)i2 * CIN + coff);
    cn[3] = *(const uint4*)(xTn + (size_t)i3 * CIN + coff);
    wt[0] = sWgt[k][0][pixS]; wt[1] = sWgt[k][1][pixS];
    wt[2] = sWgt[k][2][pixS]; wt[3] = sWgt[k][3][pixS];
  };

  auto blendOne = [&](unsigned int u0, unsigned int u1, unsigned int u2,
                      unsigned int u3, const float* wt) -> unsigned int {
    f32x2 s = up2(u0) * wt[0];       // v_pk_fma chain
    s += up2(u1) * wt[1];
    s += up2(u2) * wt[2];
    s += up2(u3) * wt[3];
    return (unsigned int)f2bf(s.x) | ((unsigned int)f2bf(s.y) << 16);
  };
  auto blendStore = [&](uint4* cn, const float* wt, int buf) {
    uint4 r;
    r.x = blendOne(cn[0].x, cn[1].x, cn[2].x, cn[3].x, wt);
    r.y = blendOne(cn[0].y, cn[1].y, cn[2].y, cn[3].y, wt);
    r.z = blendOne(cn[0].z, cn[1].z, cn[2].z, cn[3].z, wt);
    r.w = blendOne(cn[0].w, cn[1].w, cn[2].w, cn[3].w, wt);
    *(uint4*)(&sB[buf][sAddr]) = r;
  };

  bf16x8 afr[4];
  auto aload = [&](int g) {
    int k = g % 9, c2 = g / 9;
    int ch = k * 8 + c2 * 2;
#pragma unroll
    for (int s = 0; s < 2; ++s)
#pragma unroll
      for (int ot = 0; ot < 2; ++ot)
        afr[s * 2 + ot] = *(const bf16x8*)(Ag + ((size_t)((ch + s) * 16 + 2 * wv + ot) * 64 + lane) * 8);
  };

  int rdBase = (quad * 16 + (l16 ^ quad)) * 8;
  auto mfmaPhase = [&](int buf) {
#pragma unroll
    for (int s = 0; s < 2; ++s) {
      bf16x8 bfr[4];
#pragma unroll
      for (int pt = 0; pt < 4; ++pt)
        bfr[pt] = *(const bf16x8*)(&sB[buf][s * 2048 + pt * 512 + rdBase]);
#pragma unroll
      for (int pt = 0; pt < 4; ++pt) {
        acc[0][pt] = __builtin_amdgcn_mfma_f32_16x16x32_bf16(afr[s * 2 + 0], bfr[pt], acc[0][pt], 0, 0, 0);
        acc[1][pt] = __builtin_amdgcn_mfma_f32_16x16x32_bf16(afr[s * 2 + 1], bfr[pt], acc[1][pt], 0, 0, 0);
      }
    }
  };

  // prologue: g0 staged to buf0; g1 corner loads in flight (depth-2 seed)
  issue(0, cnA, wgA);
  aload(0);
  blendStore(cnA, wgA, 0);
  issue(1, cnB, wgB);
  __syncthreads();

  for (int g = 0; g < NGR; g += 2) {
    // even g: consume buf0; prefetch corners g+2 -> cnA; stage cnB(g+1) -> buf1
    if (g + 2 < NGR) issue(g + 2, cnA, wgA);
    mfmaPhase(0);
    aload(g + 1);                 // A-frag loads fly across blend+barrier
    blendStore(cnB, wgB, 1);
    __syncthreads();

    // odd g+1: consume buf1; prefetch corners g+3 -> cnB; stage cnA(g+2) -> buf0
    if (g + 3 < NGR) issue(g + 3, cnB, wgB);
    mfmaPhase(1);
    if (g + 2 < NGR) {
      aload(g + 2);
      blendStore(cnA, wgA, 0);
      __syncthreads();
    }
  }

  // Epilogue: D col = l16 (pix), row = quad*4 + r (o within 16-tile)
#pragma unroll
  for (int ot = 0; ot < 2; ++ot) {
#pragma unroll
    for (int r = 0; r < 4; ++r) {
      int o = (2 * wv + ot) * 16 + quad * 4 + r;
      unsigned short* rowp = yb + (size_t)(n * COUT + o) * HW + pixBase;
      float s = 0.f, q = 0.f;
#pragma unroll
      for (int pt = 0; pt < 4; ++pt) {
        float v = acc[ot][pt][r];
        rowp[pt * 16 + l16] = f2bf(v);
        s += v;
        q = fmaf(v, v, q);
      }
#pragma unroll
      for (int m = 8; m >= 1; m >>= 1) {
        s += __shfl_xor(s, m, 64);
        q += __shfl_xor(q, m, 64);
      }
      if (l16 == 0) {
        atomicAdd(&sumArr[o], s);
        atomicAdd(&sqArr[o], q);
      }
    }
  }
}

// ---------------------------------------------------------------------------
// BN finalize + apply (bf16 y -> fp32 out)
// ---------------------------------------------------------------------------
__global__ __launch_bounds__(256)
void bn_finalize(const float* __restrict__ sumArr, const float* __restrict__ sqArr,
                 const float* __restrict__ gamma, const float* __restrict__ beta,
                 float* __restrict__ scaleArr, float* __restrict__ shiftArr) {
  int o = threadIdx.x;
  const float inv = 1.f / (float)(NB * HW);
  float mean = sumArr[o] * inv;
  float var = sqArr[o] * inv - mean * mean;
  float sc = rsqrtf(var + 1e-5f) * gamma[o];
  scaleArr[o] = sc;
  shiftArr[o] = beta[o] - mean * sc;
}

__global__ __launch_bounds__(256)
void bn_apply(const unsigned short* __restrict__ yb,
              float* __restrict__ out,
              const float* __restrict__ scaleArr,
              const float* __restrict__ shiftArr) {
  int gid = blockIdx.x * 256 + threadIdx.x;  // < NB*COUT*HW/8
  int base = gid * 8;
  int o = (base / HW) % COUT;
  float scale = scaleArr[o], shift = shiftArr[o];
  uint4 v = ((const uint4*)yb)[gid];
  float4 a, b;
  a.x = fmaxf(fmaf(bf2f((unsigned short)(v.x & 0xffff)), scale, shift), 0.f);
  a.y = fmaxf(fmaf(bf2f((unsigned short)(v.x >> 16)), scale, shift), 0.f);
  a.z = fmaxf(fmaf(bf2f((unsigned short)(v.y & 0xffff)), scale, shift), 0.f);
  a.w = fmaxf(fmaf(bf2f((unsigned short)(v.y >> 16)), scale, shift), 0.f);
  b.x = fmaxf(fmaf(bf2f((unsigned short)(v.z & 0xffff)), scale, shift), 0.f);
  b.y = fmaxf(fmaf(bf2f((unsigned short)(v.z >> 16)), scale, shift), 0.f);
  b.z = fmaxf(fmaf(bf2f((unsigned short)(v.w & 0xffff)), scale, shift), 0.f);
  b.w = fmaxf(fmaf(bf2f((unsigned short)(v.w >> 16)), scale, shift), 0.f);
  *(float4*)&out[base] = a;
  *(float4*)&out[base + 4] = b;
}

// ---------------------------------------------------------------------------
extern "C" void kernel_launch(void* const* d_in, const int* in_sizes, int n_in,
                              void* d_out, int out_size, void* d_ws, size_t ws_size,
                              hipStream_t stream) {
  const float* x     = (const float*)d_in[0];
  const float* w_off = (const float*)d_in[1];
  const float* b_off = (const float*)d_in[2];
  const float* w     = (const float*)d_in[3];
  // d_in[4] = b : cancels exactly in BN mean-subtraction
  const float* gamma = (const float*)d_in[5];
  const float* beta  = (const float*)d_in[6];
  float* out = (float*)d_out;

  float* ws = (float*)d_ws;
  float* py = ws;                          // 331776 f
  float* px = py + 331776;
  float* mk = px + 331776;
  unsigned short* Ag  = (unsigned short*)(mk + 331776);  // 589824 u16
  unsigned short* Ag2 = Ag + 589824;                     // 73728 u16
  float* sumArr   = (float*)(Ag2 + 73728);
  float* sqArr    = sumArr + 256;
  float* scaleArr = sqArr + 256;
  float* shiftArr = scaleArr + 256;
  unsigned short* yb = (unsigned short*)(shiftArr + 256);  // 9437184 u16
  unsigned short* xT = yb + 9437184;                       // 9437184 u16

  hipMemsetAsync(sumArr, 0, 512 * sizeof(float), stream);

  dim3 gT(HW / 64, CIN / 64, NB);
  xt_convert<<<gT, 256, 0, stream>>>(x, xT);

  wa_convert<<<(NCH * 16 * 64) / 256, 256, 0, stream>>>(w, Ag);
  wa2_convert<<<(NCH * 2 * 64) / 256, 256, 0, stream>>>(w_off, Ag2);

  dim3 gO(HW / 64, NB);
  offset_gemm<<<gO, 256, 0, stream>>>(xT, Ag2, b_off, py, px, mk);

  dim3 gG(HW / 64, NB);
  fused_gemm<<<gG, 512, 0, stream>>>(xT, Ag, py, px, mk, yb, sumArr, sqArr);

  bn_finalize<<<1, 256, 0, stream>>>(sumArr, sqArr, gamma, beta, scaleArr, shiftArr);
  bn_apply<<<(NB * COUT * HW / 8) / 256, 256, 0, stream>>>(yb, out, scaleArr, shiftArr);
}